// Round 19
// baseline (154.553 us; speedup 1.0000x reference)
//
#include <hip/hip_runtime.h>
#include <math.h>
#include <limits.h>

#define Bb 32
#define Tt 16384
#define Cc 128
#define Dd 256
#define Pp 2048
#define GMAX 4096
#define TP 16
#define MSTRIDE 24

// pid as XLA-jit computes it: AlgebraicSimplifier rewrites divide(t, 7.0) ->
// multiply(t, fl(1/7)); fl(1/7) = 0x3E124925 = 0.14285714924335479736328125.
// (The r16-seq SCAN with truediv was the "beats-truth" cell 0.3047 -> scan
// right, div rule wrong. This is the untried coherent cell.)
__device__ __forceinline__ int PID(float t) {
  return (int)floorf(t * 0.14285714924335479736328125f);
}

// ---------------- Kernel A: XLA ReduceWindowRewriter radix-16 cumsum ----------
// ref = old-jax CPU path: cumsum -> reduce_window -> ReduceWindowRewriter
// (base_length=16): reshape [1024,16]; inner per-tile scans evaluated directly
// (fresh LEFT-TO-RIGHT sequential f32 sum per output); tile sums = last
// column; outer scan recursed (1024->[64,16], 64->[4,16], 4<=16 direct seq);
// combine t[i] = fl(inner0[i] + carry), ONE rounding per level.
// Tree-reassociated t may be locally non-monotone -> run-rank extraction
// (count pid CHANGES, mirrors reference's new/cumsum).
__global__ __launch_bounds__(256) void scan_k(const float* __restrict__ td,
                                              int* __restrict__ starts,
                                              int* __restrict__ ngroups) {
  __shared__ float buf[Tt];            // 64 KB: the row
  __shared__ float S0[1024], P0[1024]; // tile sums / inclusive radix scan of S0
  __shared__ float S1[64],  P1[64];
  __shared__ float P2s[4];
  __shared__ int   cnt[256];

  const int b = blockIdx.x;
  const int tid = threadIdx.x;
  const float* row = td + (size_t)b * Tt;

  const float4* r4 = (const float4*)row;
  float4* b4 = (float4*)buf;
  for (int i = tid; i < Tt / 4; i += 256) b4[i] = r4[i];
  __syncthreads();

  // S0[k] = sequential 16-sum of tile k (== reduce_window output at j=15)
  for (int k = tid; k < 1024; k += 256) {
    const float* p = buf + k * 16;
    float s = p[0];
    #pragma unroll
    for (int j = 1; j < 16; ++j) s += p[j];
    S0[k] = s;
  }
  __syncthreads();

  // S1[k1] = sequential 16-sum over S0 tile k1
  if (tid < 64) {
    const float* p = S0 + tid * 16;
    float s = p[0];
    #pragma unroll
    for (int j = 1; j < 16; ++j) s += p[j];
    S1[tid] = s;
  }
  __syncthreads();

  // S2 (length 4) + its direct sequential scan P2s
  if (tid == 0) {
    float run = 0.f;
    for (int m = 0; m < 4; ++m) {
      const float* p = S1 + m * 16;
      float s = p[0];
      #pragma unroll
      for (int j = 1; j < 16; ++j) s += p[j];
      run = (m == 0) ? s : run + s;
      P2s[m] = run;
    }
  }
  __syncthreads();

  // P1[k] = inclusive scan of S1: fl( seq(S1 tile up to k) + carry from P2s )
  if (tid < 64) {
    const int k2 = tid >> 4, j1 = tid & 15;
    const float* p = S1 + (k2 << 4);
    float s = p[0];
    for (int j = 1; j <= j1; ++j) s += p[j];
    P1[tid] = (k2 == 0) ? s : s + P2s[k2 - 1];
  }
  __syncthreads();

  // P0[k] = inclusive scan of S0: fl( seq(S0 tile up to k) + P1[k1-1] )
  for (int k = tid; k < 1024; k += 256) {
    const int k1 = k >> 4, j = k & 15;
    const float* p = S0 + (k1 << 4);
    float s = p[0];
    for (int jj = 1; jj <= j; ++jj) s += p[jj];
    P0[k] = (k1 == 0) ? s : s + P1[k1 - 1];
  }
  __syncthreads();

  // extraction: thread owns 64 consecutive elements = tiles 4tid..4tid+3
  // t[16k+j] = (k==0) ? inner0 : fl(inner0 + P0[k-1]), inner0 = seq within tile
  const int base = tid * 64;
  int pprev0;
  if (tid == 0) pprev0 = INT_MIN;
  else {
    const int k = 4 * tid - 1;                 // last elem of prev chunk = full tile k
    const float t = (k == 0) ? S0[0] : S0[k] + P0[k - 1];
    pprev0 = PID(t);
  }

  // pass 1: count pid changes
  int pprev = pprev0, count = 0;
  for (int tk = 0; tk < 4; ++tk) {
    const int k = 4 * tid + tk;
    const float carry = (k == 0) ? 0.f : P0[k - 1];
    const float* p = buf + k * 16;
    float s = 0.f;
    #pragma unroll
    for (int j = 0; j < 16; ++j) {
      s = (j == 0) ? p[0] : s + p[j];
      const float t = (k == 0) ? s : s + carry;
      const int pid = PID(t);
      count += (pid != pprev);
      pprev = pid;
    }
  }
  cnt[tid] = count;
  __syncthreads();
  if (tid == 0) {
    int run = 0;
    for (int k = 0; k < 256; ++k) { int c = cnt[k]; cnt[k] = run; run += c; }
  }
  __syncthreads();

  // pass 2: emit starts[rank]
  int r = cnt[tid];
  pprev = pprev0;
  int* stb = starts + b * GMAX;
  for (int tk = 0; tk < 4; ++tk) {
    const int k = 4 * tid + tk;
    const float carry = (k == 0) ? 0.f : P0[k - 1];
    const float* p = buf + k * 16;
    float s = 0.f;
    #pragma unroll
    for (int j = 0; j < 16; ++j) {
      s = (j == 0) ? p[0] : s + p[j];
      const float t = (k == 0) ? s : s + carry;
      const int pid = PID(t);
      if (pid != pprev) stb[r++] = k * 16 + j;
      pprev = pid;
    }
  }
  if (tid == 255) {
    ngroups[b] = r;
    stb[r] = Tt;
  }
}

// ---------------- Kernel B: fused group-mean + linear projection ----------------
__global__ __launch_bounds__(256) void embed_k(const float* __restrict__ x,
                                               const float* __restrict__ Wm,
                                               const float* __restrict__ bias,
                                               const int* __restrict__ starts,
                                               const int* __restrict__ ngroups,
                                               float* __restrict__ out_patches,
                                               float* __restrict__ out_valid) {
  const int blk = blockIdx.x;
  const int b = blk >> 7;
  const int pt = (blk & 127) * TP;
  const int tid = threadIdx.x;
  const int ng = ngroups[b];
  const int off = Pp - ng;             // slot p valid iff p >= off

  const float bias_v = bias[tid];
  const size_t obase = ((size_t)b * Pp + pt) * Dd + tid;

  if (tid < TP)
    out_valid[(size_t)b * Pp + pt + tid] = (pt + tid >= off) ? 1.0f : 0.0f;

  if (pt + TP <= off) {                // whole tile is padding -> bias
    #pragma unroll
    for (int j = 0; j < TP; ++j) out_patches[obase + (size_t)j * Dd] = bias_v;
    return;
  }

  __shared__ float mean_l[Cc * MSTRIDE];
  const int wave = tid >> 6, lane = tid & 63;
  const int* st = starts + b * GMAX;

  #pragma unroll
  for (int jj = 0; jj < 4; ++jj) {
    const int j = wave * 4 + jj;
    const int g = pt + j - off;
    float m0 = 0.f, m1 = 0.f;
    if (g >= 0) {
      const int s = st[g], e = st[g + 1];
      float s0 = 0.f, s1 = 0.f;
      const float* xp = x + ((size_t)b * Tt + s) * Cc + lane;
      for (int t = s; t < e; ++t, xp += Cc) { s0 += xp[0]; s1 += xp[64]; }
      const float c = (float)(e - s);
      m0 = s0 / c;
      m1 = s1 / c;
    }
    mean_l[lane * MSTRIDE + j] = m0;
    mean_l[(lane + 64) * MSTRIDE + j] = m1;
  }
  __syncthreads();

  float acc[16];
  #pragma unroll
  for (int j = 0; j < 16; ++j) acc[j] = 0.f;

  const float* wp = Wm + tid;
  #pragma unroll 4
  for (int c = 0; c < Cc; ++c) {
    const float w = wp[(size_t)c * Dd];
    const float4* mp = (const float4*)(mean_l + c * MSTRIDE);
    const float4 m0 = mp[0], m1 = mp[1], m2 = mp[2], m3 = mp[3];
    acc[0]  += m0.x * w; acc[1]  += m0.y * w; acc[2]  += m0.z * w; acc[3]  += m0.w * w;
    acc[4]  += m1.x * w; acc[5]  += m1.y * w; acc[6]  += m1.z * w; acc[7]  += m1.w * w;
    acc[8]  += m2.x * w; acc[9]  += m2.y * w; acc[10] += m2.z * w; acc[11] += m2.w * w;
    acc[12] += m3.x * w; acc[13] += m3.y * w; acc[14] += m3.z * w; acc[15] += m3.w * w;
  }

  #pragma unroll
  for (int j = 0; j < 16; ++j)
    out_patches[obase + (size_t)j * Dd] = acc[j] + bias_v;
}

extern "C" void kernel_launch(void* const* d_in, const int* in_sizes, int n_in,
                              void* d_out, int out_size, void* d_ws, size_t ws_size,
                              hipStream_t stream) {
  const float* x    = (const float*)d_in[0];
  const float* td   = (const float*)d_in[1];
  const float* Wm   = (const float*)d_in[2];
  const float* bias = (const float*)d_in[3];
  float* out = (float*)d_out;

  int* starts  = (int*)d_ws;
  int* ngroups = (int*)((char*)d_ws + (size_t)Bb * GMAX * 4);

  scan_k<<<Bb, 256, 0, stream>>>(td, starts, ngroups);
  embed_k<<<Bb * (Pp / TP), 256, 0, stream>>>(x, Wm, bias, starts, ngroups,
                                              out, out + (size_t)Bb * Pp * Dd);
}

// Round 20
// 144.111 us; speedup vs baseline: 1.0725x; 1.0725x over previous
//
#include <hip/hip_runtime.h>
#include <math.h>
#include <limits.h>

#define Bb 32
#define Tt 16384
#define Cc 128
#define Dd 256
#define Pp 2048
#define GMAX 4096
#define TP 16

// pid as XLA-jit computes it: divide(t,7) -> multiply(t, fl(1/7)).
// fl(1/7) = 0x3E124925. VERIFIED passing combination (R19) — do not touch.
__device__ __forceinline__ int PID(float t) {
  return (int)floorf(t * 0.14285714924335479736328125f);
}

// ---------------- Kernel A: XLA ReduceWindowRewriter radix-16 cumsum ----------
// VERIFIED producer replica (R19, absmax 0.0039): base-16 radix scan with
// sequential window eval + rcp-mul pid. Unchanged.
__global__ __launch_bounds__(256) void scan_k(const float* __restrict__ td,
                                              int* __restrict__ starts,
                                              int* __restrict__ ngroups) {
  __shared__ float buf[Tt];
  __shared__ float S0[1024], P0[1024];
  __shared__ float S1[64],  P1[64];
  __shared__ float P2s[4];
  __shared__ int   cnt[256];

  const int b = blockIdx.x;
  const int tid = threadIdx.x;
  const float* row = td + (size_t)b * Tt;

  const float4* r4 = (const float4*)row;
  float4* b4 = (float4*)buf;
  for (int i = tid; i < Tt / 4; i += 256) b4[i] = r4[i];
  __syncthreads();

  for (int k = tid; k < 1024; k += 256) {
    const float* p = buf + k * 16;
    float s = p[0];
    #pragma unroll
    for (int j = 1; j < 16; ++j) s += p[j];
    S0[k] = s;
  }
  __syncthreads();

  if (tid < 64) {
    const float* p = S0 + tid * 16;
    float s = p[0];
    #pragma unroll
    for (int j = 1; j < 16; ++j) s += p[j];
    S1[tid] = s;
  }
  __syncthreads();

  if (tid == 0) {
    float run = 0.f;
    for (int m = 0; m < 4; ++m) {
      const float* p = S1 + m * 16;
      float s = p[0];
      #pragma unroll
      for (int j = 1; j < 16; ++j) s += p[j];
      run = (m == 0) ? s : run + s;
      P2s[m] = run;
    }
  }
  __syncthreads();

  if (tid < 64) {
    const int k2 = tid >> 4, j1 = tid & 15;
    const float* p = S1 + (k2 << 4);
    float s = p[0];
    for (int j = 1; j <= j1; ++j) s += p[j];
    P1[tid] = (k2 == 0) ? s : s + P2s[k2 - 1];
  }
  __syncthreads();

  for (int k = tid; k < 1024; k += 256) {
    const int k1 = k >> 4, j = k & 15;
    const float* p = S0 + (k1 << 4);
    float s = p[0];
    for (int jj = 1; jj <= j; ++jj) s += p[jj];
    P0[k] = (k1 == 0) ? s : s + P1[k1 - 1];
  }
  __syncthreads();

  const int base = tid * 64;
  int pprev0;
  if (tid == 0) pprev0 = INT_MIN;
  else {
    const int k = 4 * tid - 1;
    const float t = (k == 0) ? S0[0] : S0[k] + P0[k - 1];
    pprev0 = PID(t);
  }

  int pprev = pprev0, count = 0;
  for (int tk = 0; tk < 4; ++tk) {
    const int k = 4 * tid + tk;
    const float carry = (k == 0) ? 0.f : P0[k - 1];
    const float* p = buf + k * 16;
    float s = 0.f;
    #pragma unroll
    for (int j = 0; j < 16; ++j) {
      s = (j == 0) ? p[0] : s + p[j];
      const float t = (k == 0) ? s : s + carry;
      const int pid = PID(t);
      count += (pid != pprev);
      pprev = pid;
    }
  }
  cnt[tid] = count;
  __syncthreads();
  if (tid == 0) {
    int run = 0;
    for (int k = 0; k < 256; ++k) { int c = cnt[k]; cnt[k] = run; run += c; }
  }
  __syncthreads();

  int r = cnt[tid];
  pprev = pprev0;
  int* stb = starts + b * GMAX;
  for (int tk = 0; tk < 4; ++tk) {
    const int k = 4 * tid + tk;
    const float carry = (k == 0) ? 0.f : P0[k - 1];
    const float* p = buf + k * 16;
    float s = 0.f;
    #pragma unroll
    for (int j = 0; j < 16; ++j) {
      s = (j == 0) ? p[0] : s + p[j];
      const float t = (k == 0) ? s : s + carry;
      const int pid = PID(t);
      if (pid != pprev) stb[r++] = k * 16 + j;
      pprev = pid;
    }
  }
  if (tid == 255) {
    ngroups[b] = r;
    stb[r] = Tt;
  }
}

// ---------------- Kernel B: fused group-mean + linear projection --------------
// Mean phase: lane = (row-parity r2, channel-quad cq). float4 loads (16B/lane),
// 2 rows in flight, unroll-2 (4 independent acc chains), shfl_xor(32) merge.
// Mean tile is PATCH-MAJOR [16][128]: float4 writes conflict-free; FMA reads
// are uniform b128 broadcasts (conflict-free).
__global__ __launch_bounds__(256) void embed_k(const float* __restrict__ x,
                                               const float* __restrict__ Wm,
                                               const float* __restrict__ bias,
                                               const int* __restrict__ starts,
                                               const int* __restrict__ ngroups,
                                               float* __restrict__ out_patches,
                                               float* __restrict__ out_valid) {
  const int blk = blockIdx.x;
  const int b = blk >> 7;
  const int pt = (blk & 127) * TP;
  const int tid = threadIdx.x;
  const int ng = ngroups[b];
  const int off = Pp - ng;             // slot p valid iff p >= off

  const float bias_v = bias[tid];
  const size_t obase = ((size_t)b * Pp + pt) * Dd + tid;

  if (tid < TP)
    out_valid[(size_t)b * Pp + pt + tid] = (pt + tid >= off) ? 1.0f : 0.0f;

  if (pt + TP <= off) {                // whole tile is padding -> bias
    #pragma unroll
    for (int j = 0; j < TP; ++j) out_patches[obase + (size_t)j * Dd] = bias_v;
    return;
  }

  __shared__ float mean_l[TP][Cc];     // 8 KB, patch-major
  const int wave = tid >> 6, lane = tid & 63;
  const int r2 = lane >> 5;            // row parity
  const int cq = lane & 31;            // channel quad -> channels 4cq..4cq+3
  const int* st = starts + b * GMAX;

  #pragma unroll
  for (int jj = 0; jj < 4; ++jj) {
    const int j = wave * 4 + jj;
    const int g = pt + j - off;
    float4 a0 = make_float4(0.f, 0.f, 0.f, 0.f);
    float4 a1 = make_float4(0.f, 0.f, 0.f, 0.f);
    int n = 0;
    if (g >= 0) {
      const int s = st[g], e = st[g + 1];
      n = e - s;
      const float* xp = x + ((size_t)b * Tt + s) * Cc + 4 * cq;
      int i = r2;
      for (; i + 2 < n; i += 4) {      // 2 float4 loads in flight per lane
        const float4 v0 = *(const float4*)(xp + (size_t)i * Cc);
        const float4 v1 = *(const float4*)(xp + (size_t)(i + 2) * Cc);
        a0.x += v0.x; a0.y += v0.y; a0.z += v0.z; a0.w += v0.w;
        a1.x += v1.x; a1.y += v1.y; a1.z += v1.z; a1.w += v1.w;
      }
      if (i < n) {
        const float4 v = *(const float4*)(xp + (size_t)i * Cc);
        a0.x += v.x; a0.y += v.y; a0.z += v.z; a0.w += v.w;
      }
    }
    a0.x += a1.x; a0.y += a1.y; a0.z += a1.z; a0.w += a1.w;
    a0.x += __shfl_xor(a0.x, 32);      // merge row parities
    a0.y += __shfl_xor(a0.y, 32);
    a0.z += __shfl_xor(a0.z, 32);
    a0.w += __shfl_xor(a0.w, 32);
    if (r2 == 0) {
      float4 m = make_float4(0.f, 0.f, 0.f, 0.f);
      if (g >= 0) {
        const float fn = (float)n;
        m = make_float4(a0.x / fn, a0.y / fn, a0.z / fn, a0.w / fn);
      }
      *(float4*)(&mean_l[j][4 * cq]) = m;   // conflict-free vector write
    }
  }
  __syncthreads();

  float acc[16];
  #pragma unroll
  for (int j = 0; j < 16; ++j) acc[j] = 0.f;

  const float* wp = Wm + tid;          // thread owns column d = tid
  for (int q = 0; q < Cc / 4; ++q) {   // c-quad loop
    const float w0 = wp[(4 * q + 0) * Dd];
    const float w1 = wp[(4 * q + 1) * Dd];
    const float w2 = wp[(4 * q + 2) * Dd];
    const float w3 = wp[(4 * q + 3) * Dd];
    #pragma unroll
    for (int j = 0; j < 16; ++j) {
      const float4 m = *(const float4*)(&mean_l[j][4 * q]);  // uniform b128
      float a = acc[j];
      a = fmaf(m.x, w0, a);
      a = fmaf(m.y, w1, a);
      a = fmaf(m.z, w2, a);
      a = fmaf(m.w, w3, a);
      acc[j] = a;
    }
  }

  #pragma unroll
  for (int j = 0; j < 16; ++j)
    out_patches[obase + (size_t)j * Dd] = acc[j] + bias_v;
}

extern "C" void kernel_launch(void* const* d_in, const int* in_sizes, int n_in,
                              void* d_out, int out_size, void* d_ws, size_t ws_size,
                              hipStream_t stream) {
  const float* x    = (const float*)d_in[0];
  const float* td   = (const float*)d_in[1];
  const float* Wm   = (const float*)d_in[2];
  const float* bias = (const float*)d_in[3];
  float* out = (float*)d_out;

  int* starts  = (int*)d_ws;
  int* ngroups = (int*)((char*)d_ws + (size_t)Bb * GMAX * 4);

  scan_k<<<Bb, 256, 0, stream>>>(td, starts, ngroups);
  embed_k<<<Bb * (Pp / TP), 256, 0, stream>>>(x, Wm, bias, starts, ngroups,
                                              out, out + (size_t)Bb * Pp * Dd);
}